// Round 1
// 365.611 us; speedup vs baseline: 1.0003x; 1.0003x over previous
//
#include <hip/hip_runtime.h>

// Problem: B=4, M_IN=16, M_OUT=32, C=32
// x: (B, M_IN, C, C, C, C) fp32, 67,108,864 elements = 256 MiB
// out[b,n,i,c] = sum_m s_i[b,m,c] * W[m,n],  W = alpha+beta+gamma+delta
//   s_0 = s_1 = x.sum(axes 3,4,5)  (keeps c2)
//   s_2       = x.sum(axes 2,4,5)  (keeps c3)
//   s_3       = x.sum(axes 2,3,5)  (keeps c4)
//
// Two kernels, no atomics, no zero pass:
//   reduce_k: one block per (b,m,c2) slab (2048 blocks) streams 128 KiB and
//     writes BLOCK-EXCLUSIVE partials with plain stores:
//       p1[bid]          = full s1[b,m,c2]              (2048 floats)
//       p3[bid*32 + c3]  = partial of s3 over this c2   (65536 floats)
//       p4[bid*32 + c4]  = partial of s4 over this c2   (65536 floats)
//   finalize_k: 16 blocks = (b, i4); reduces partials over c2 (L2-resident,
//     64 KB per block) into LDS, applies W, writes out.
//
// ws floats: p1[0..2048) | p3[2048..67584) | p4[67584..133120)  (= 532 KB)

#define P3_OFF 2048
#define P4_OFF (2048 + 65536)

__global__ __launch_bounds__(256) void reduce_k(const float* __restrict__ x,
                                                float* __restrict__ ws) {
    const int t   = threadIdx.x;        // 0..255
    const int bid = blockIdx.x;         // (bm<<5) | c2 ; bm = b*16+m
    const int lane = t & 63;
    const int wv   = t >> 6;            // wave id 0..3

    __shared__ float lds3[4][32];       // per-wave, per-c3 partial
    __shared__ float lds4[32];          // per-c4 partial (one group of 8 per c4)
    __shared__ float lds1[4];           // per-wave total

    // Slab of 32768 contiguous floats = 8192 float4s for this (b,m,c2)
    const float4* xv = (const float4*)x + (size_t)bid * 8192;

    float total = 0.0f;
    #pragma unroll
    for (int it = 0; it < 32; ++it) {   // it == c3 (block-uniform)
        // coalesced: per iteration the block reads 4 KiB contiguous
        float4 v = xv[it * 256 + t];
        float s = (v.x + v.y) + (v.z + v.w);
        total += s;
        // wave-wide butterfly reduce of s -> s3 contribution for c3=it
        #pragma unroll
        for (int off = 1; off < 64; off <<= 1)
            s += __shfl_xor(s, off, 64);
        if (lane == 0) lds3[wv][it] = s;
    }

    // s4: c4 = t>>3 is fixed per thread; reduce total over each group of 8 lanes
    float g = total;
    g += __shfl_xor(g, 1, 64);
    g += __shfl_xor(g, 2, 64);
    g += __shfl_xor(g, 4, 64);
    if ((t & 7) == 0) lds4[t >> 3] = g;   // exactly one writer per c4 in the block

    // s1: continue to full-wave total
    float wsum = g;
    wsum += __shfl_xor(wsum, 8, 64);
    wsum += __shfl_xor(wsum, 16, 64);
    wsum += __shfl_xor(wsum, 32, 64);
    if (lane == 0) lds1[wv] = wsum;

    __syncthreads();

    // Block-exclusive plain stores — no zero pass, no atomics.
    if (t < 32) {
        float v3 = lds3[0][t] + lds3[1][t] + lds3[2][t] + lds3[3][t];
        ws[P3_OFF + bid * 32 + t] = v3;
        ws[P4_OFF + bid * 32 + t] = lds4[t];
    }
    if (t == 0)
        ws[bid] = lds1[0] + lds1[1] + lds1[2] + lds1[3];
}

__global__ __launch_bounds__(256) void finalize_k(const float* __restrict__ ws,
                                                  const float* __restrict__ alpha,
                                                  const float* __restrict__ beta,
                                                  const float* __restrict__ gamma,
                                                  const float* __restrict__ delta,
                                                  float* __restrict__ out) {
    __shared__ float W[512];            // W[m*32+n] = sum of the 4 weight mats
    __shared__ float S[16][32];         // S[m][c] = s_{i4}[b][m][c]
    const int t  = threadIdx.x;
    const int b  = blockIdx.x >> 2;     // 0..3
    const int i4 = blockIdx.x & 3;      // 0..3

    #pragma unroll
    for (int i = t; i < 512; i += 256)
        W[i] = alpha[i] + beta[i] + gamma[i] + delta[i];

    if (i4 <= 1) {
        // s1 == s2: p1[bid] is already the full value
        #pragma unroll
        for (int i = t; i < 512; i += 256) {
            int m = i >> 5, c = i & 31;
            S[m][c] = ws[(b * 16 + m) * 32 + c];
        }
    } else {
        // reduce p3/p4 over c2 (32 partials per (m,c)); 64 KB, L2-resident
        const float* p = ws + (i4 == 2 ? P3_OFF : P4_OFF);
        #pragma unroll
        for (int i = t; i < 512; i += 256) {
            int m = i >> 5, c = i & 31;
            const float* q = p + (b * 16 + m) * 1024 + c;   // + c2*32 below
            float acc = 0.0f;
            #pragma unroll
            for (int c2 = 0; c2 < 32; ++c2)
                acc += q[c2 * 32];
            S[m][c] = acc;
        }
    }
    __syncthreads();

    // 1024 outputs per block: out[b, n, i4, c] for all (n, c)
    #pragma unroll
    for (int k = 0; k < 4; ++k) {
        int idx = k * 256 + t;          // 0..1023
        int n = idx >> 5, c = idx & 31; // n broadcast per 32 lanes, c coalesced
        float acc = 0.0f;
        #pragma unroll
        for (int m = 0; m < 16; ++m)
            acc += S[m][c] * W[m * 32 + n];
        out[((b * 32 + n) * 4 + i4) * 32 + c] = acc;
    }
}

extern "C" void kernel_launch(void* const* d_in, const int* in_sizes, int n_in,
                              void* d_out, int out_size, void* d_ws, size_t ws_size,
                              hipStream_t stream) {
    const float* x     = (const float*)d_in[0];
    const float* alpha = (const float*)d_in[1];
    const float* beta  = (const float*)d_in[2];
    const float* gamma = (const float*)d_in[3];
    const float* delta = (const float*)d_in[4];
    float* out = (float*)d_out;
    float* ws  = (float*)d_ws;

    reduce_k<<<2048, 256, 0, stream>>>(x, ws);    // streaming pass, plain stores
    finalize_k<<<16, 256, 0, stream>>>(ws, alpha, beta, gamma, delta, out);
}